// Round 4
// baseline (497.299 us; speedup 1.0000x reference)
//
#include <hip/hip_runtime.h>
#include <hip/hip_fp16.h>
#include <math.h>

#define DIM 128
#define VOXSTRIDE (DIM*DIM*DIM)
#define CATT 23
#define NEARF 0.2f
#define FARF 6.0f
#define WS_NEED ((size_t)VOXSTRIDE * 64ull)

typedef unsigned uintv4 __attribute__((ext_vector_type(4)));

// d_init: linspace(NEAR, FAR, 256)
__device__ __forceinline__ float d_init_val(int i) {
    float t = (float)i * (1.0f / 255.0f);
    return NEARF * (1.0f - t) + FARF * t;
}
// d_coarse: linspace(NEAR, FAR, 64)
__device__ __forceinline__ float d_coarse_val(int i) {
    float t = (float)i * (1.0f / 63.0f);
    return NEARF * (1.0f - t) + FARF * t;
}

// ---------- corner setup ----------
__device__ __forceinline__ void setup_ac_border(float x, float y, float z,
                                                float* i0, float* fr) {
    float c[3] = {x, y, z};
#pragma unroll
    for (int a = 0; a < 3; a++) {
        float v = (c[a] + 1.0f) * 0.5f * 127.0f;
        v = fminf(fmaxf(v, 0.0f), 127.0f);
        float f = floorf(v);
        i0[a] = f; fr[a] = v - f;
    }
}
__device__ __forceinline__ void setup_nac_zeros(float x, float y, float z,
                                                float* i0, float* fr) {
    float c[3] = {x, y, z};
#pragma unroll
    for (int a = 0; a < 3; a++) {
        float v = ((c[a] + 1.0f) * 128.0f - 1.0f) * 0.5f;
        float f = floorf(v);
        i0[a] = f; fr[a] = v - f;
    }
}

// trilinear SDF from fp32 volume (align_corners=True, border)
__device__ __forceinline__ float tri_sdf_vol(const float* __restrict__ vol,
                                             float x, float y, float z) {
    float i0[3], fr[3];
    setup_ac_border(x, y, z, i0, fr);
    float res = 0.0f;
#pragma unroll
    for (int corner = 0; corner < 8; corner++) {
        float w = 1.0f;
        int gi[3];
#pragma unroll
        for (int a = 0; a < 3; a++) {
            int off = (corner >> a) & 1;
            float iv = i0[a] + (float)off;
            w *= off ? fr[a] : (1.0f - fr[a]);
            iv = fminf(fmaxf(iv, 0.0f), 127.0f);
            gi[a] = (int)iv;
        }
        int idx = (gi[0] * DIM + gi[1]) * DIM + gi[2];
        res += vol[idx] * w;
    }
    return res;
}

// trilinear SDF from packed records (fp32 at dword 12 of 16-dword record)
__device__ __forceinline__ float tri_sdf_rec(const float* __restrict__ recf,
                                             float x, float y, float z) {
    float i0[3], fr[3];
    setup_ac_border(x, y, z, i0, fr);
    float res = 0.0f;
#pragma unroll
    for (int corner = 0; corner < 8; corner++) {
        float w = 1.0f;
        int gi[3];
#pragma unroll
        for (int a = 0; a < 3; a++) {
            int off = (corner >> a) & 1;
            float iv = i0[a] + (float)off;
            w *= off ? fr[a] : (1.0f - fr[a]);
            iv = fminf(fmaxf(iv, 0.0f), 127.0f);
            gi[a] = (int)iv;
        }
        int idx = (gi[0] * DIM + gi[1]) * DIM + gi[2];
        res += recf[idx * 16 + 12] * w;
    }
    return res;
}

__device__ __forceinline__ void unpack16(uintv4 a, uintv4 b, float* v) {
    unsigned us[8] = {a.x, a.y, a.z, a.w, b.x, b.y, b.z, b.w};
#pragma unroll
    for (int i = 0; i < 8; i++) {
        v[2 * i]     = __half2float(__ushort_as_half((unsigned short)(us[i] & 0xffffu)));
        v[2 * i + 1] = __half2float(__ushort_as_half((unsigned short)(us[i] >> 16)));
    }
}

// attr trilinear (w-weighted, NOT tau-weighted) from packed fp16 records
__device__ __forceinline__ void tri_attr_rec(const uintv4* __restrict__ recs,
                                             float x, float y, float z,
                                             float* acc, int half) {
    float i0[3], fr[3];
    setup_nac_zeros(x, y, z, i0, fr);
#pragma unroll
    for (int corner = 0; corner < 8; corner++) {
        float w = 1.0f;
        bool valid = true;
        int gi[3];
#pragma unroll
        for (int a = 0; a < 3; a++) {
            int off = (corner >> a) & 1;
            float iv = i0[a] + (float)off;
            w *= off ? fr[a] : (1.0f - fr[a]);
            valid = valid && (iv >= 0.0f) && (iv <= 127.0f);
            iv = fminf(fmaxf(iv, 0.0f), 127.0f);
            gi[a] = (int)iv;
        }
        if (!valid) continue;
        int idx = (gi[0] * DIM + gi[1]) * DIM + gi[2];
        const uintv4* q = recs + (size_t)idx * 4 + half;  // h0: q0,q1; h1: q1,q2
        uintv4 qa = q[0], qb = q[1];
        float vals[16];
        unpack16(qa, qb, vals);
        if (half == 0) {
#pragma unroll
            for (int c = 0; c < 12; c++) acc[c] += w * vals[c];
        } else {
#pragma unroll
            for (int c = 0; c < 11; c++) acc[c] += w * vals[c + 4];
        }
    }
}

// fallback: fp32 planes
__device__ __forceinline__ void tri_attr_planes(const float* __restrict__ vol,
                                                float x, float y, float z,
                                                float* acc, int half) {
    float i0[3], fr[3];
    setup_nac_zeros(x, y, z, i0, fr);
    int c0 = half ? 12 : 0;
    int nc = half ? 11 : 12;
#pragma unroll
    for (int corner = 0; corner < 8; corner++) {
        float w = 1.0f;
        bool valid = true;
        int gi[3];
#pragma unroll
        for (int a = 0; a < 3; a++) {
            int off = (corner >> a) & 1;
            float iv = i0[a] + (float)off;
            w *= off ? fr[a] : (1.0f - fr[a]);
            valid = valid && (iv >= 0.0f) && (iv <= 127.0f);
            iv = fminf(fmaxf(iv, 0.0f), 127.0f);
            gi[a] = (int)iv;
        }
        if (!valid) continue;
        int idx = (gi[0] * DIM + gi[1]) * DIM + gi[2];
        for (int c = 0; c < nc; c++)
            acc[c] += w * vol[(c0 + c) * VOXSTRIDE + idx];
    }
}

// ---------- repack: nontemporal streaming ----------
__global__ __launch_bounds__(256) void repack_kernel(
    const float* __restrict__ attr, const float* __restrict__ sdfv,
    uintv4* __restrict__ recs) {
    int v = blockIdx.x * 256 + threadIdx.x;
    float a[24];
#pragma unroll
    for (int c = 0; c < CATT; c++)
        a[c] = __builtin_nontemporal_load(attr + (size_t)c * VOXSTRIDE + v);
    a[23] = 0.0f;
    float s = sdfv[v];   // cached: phase-1 reuses the sdf volume
    unsigned u[12];
#pragma unroll
    for (int p = 0; p < 12; p++) {
        __half2 h = __float22half2_rn(make_float2(a[2 * p], a[2 * p + 1]));
        u[p] = __builtin_bit_cast(unsigned, h);
    }
    uintv4* dst = recs + (size_t)v * 4;
    uintv4 q0 = {u[0], u[1], u[2], u[3]};
    uintv4 q1 = {u[4], u[5], u[6], u[7]};
    uintv4 q2 = {u[8], u[9], u[10], u[11]};
    uintv4 q3 = {__float_as_uint(s), 0u, 0u, 0u};
    __builtin_nontemporal_store(q0, dst);
    __builtin_nontemporal_store(q1, dst + 1);
    __builtin_nontemporal_store(q2, dst + 2);
    __builtin_nontemporal_store(q3, dst + 3);
}

// ---------- wave-level scans/reductions (width 64, no barriers) ----------
__device__ __forceinline__ float wave_scan_prod(float v, int lane) {
#pragma unroll
    for (int off = 1; off < 64; off <<= 1) {
        float o = __shfl_up(v, off, 64);
        if (lane >= off) v *= o;
    }
    return v;
}
__device__ __forceinline__ float wave_scan_add(float v, int lane) {
#pragma unroll
    for (int off = 1; off < 64; off <<= 1) {
        float o = __shfl_up(v, off, 64);
        if (lane >= off) v += o;
    }
    return v;
}
__device__ __forceinline__ float wave_reduce_add(float v) {
#pragma unroll
    for (int m = 32; m >= 1; m >>= 1) v += __shfl_xor(v, m, 64);
    return v;
}

template <bool PACKED>
__global__ __launch_bounds__(256, 4) void volrender_kernel(
    const float* __restrict__ rays,
    const float* __restrict__ attr,
    const float* __restrict__ sdfv,
    const uintv4* __restrict__ recs,
    const float* __restrict__ lnb,
    float* __restrict__ out, int R) {
    __shared__ float s_cdf[256];
    __shared__ float s_dfine[64];
    __shared__ float s_dall[128];
    __shared__ float s_xn[3][128];
    __shared__ float s_tau[128];
    __shared__ float s_pA[4], s_pB[4];
    __shared__ float s_pC;
    __shared__ float s_wred[4][16];
    __shared__ float s_sum[26];

    const int r = blockIdx.x;
    const int tid = threadIdx.x;
    const int lane = tid & 63;
    const int wv = tid >> 6;

    float ox = rays[r * 6 + 0], oy = rays[r * 6 + 1], oz = rays[r * 6 + 2];
    float dx = rays[r * 6 + 3], dy = rays[r * 6 + 4], dz = rays[r * 6 + 5];
    dx = (fabsf(dx) < 1e-6f) ? 1e-6f : dx;
    dy = (fabsf(dy) < 1e-6f) ? 1e-6f : dy;
    dz = (fabsf(dz) < 1e-6f) ? 1e-6f : dz;
    float dr = sqrtf(dx * dx + dy * dy + dz * dz);
    float invdr = 1.0f / dr;
    dx *= invdr; dy *= invdr; dz *= invdr;

    const float beta = expf(lnb[0] * 10.0f);
    const float alpha = 1.0f / beta;
    const float innorm = 2.0f / 5.12f;

    // ================= Phase 1: 256 init samples =================
    float d0 = d_init_val(tid);
    float sdf0;
    {
        float px = ox + dx * d0, py = oy + dy * d0, pz = oz + dz * d0;
        sdf0 = tri_sdf_vol(sdfv, px * innorm - 1.0f, py * innorm - 1.0f,
                           pz * innorm - 1.0f);
    }
    float delta0 = (tid < 255) ? (d_init_val(tid + 1) - d0) : 1e10f;
    float e0 = expf(-fabsf(sdf0) / beta);
    float sig0 = alpha * ((sdf0 >= 0.0f) ? 0.5f * e0 : (1.0f - 0.5f * e0));
    float tr0 = expf(-sig0 * delta0);
    float a0 = 1.0f - tr0;

    // exclusive product scan (transmittance)
    float inclp = wave_scan_prod(tr0 + 1e-10f, lane);
    if (lane == 63) s_pA[wv] = inclp;
    __syncthreads();                                  // B1
    float offp = 1.0f;
#pragma unroll
    for (int j = 0; j < 3; j++) if (j < wv) offp *= s_pA[j];
    float exclp = __shfl_up(inclp, 1, 64);
    if (lane == 0) exclp = 1.0f;
    float T0 = exclp * offp;
    float w0 = a0 * T0;

    // exclusive add scan (cdf)
    float wp = (tid < 255) ? (w0 + 1e-5f) : 0.0f;
    float incla = wave_scan_add(wp, lane);
    if (lane == 63) s_pB[wv] = incla;
    __syncthreads();                                  // B2
    float offa = 0.0f, tot = 0.0f;
#pragma unroll
    for (int j = 0; j < 4; j++) {
        float pj = s_pB[j];
        tot += pj;
        if (j < wv) offa += pj;
    }
    float excla = __shfl_up(incla, 1, 64);
    if (lane == 0) excla = 0.0f;
    float invw = 1.0f / tot;
    s_cdf[tid] = (excla + offa) * invw;               // cdf[0]=0, cdf[255]=1
    __syncthreads();                                  // B3

    // ---- sample_pdf ----
    if (tid < 64) {
        float u = ((float)tid + 0.5f) * (1.0f / 64.0f);
        int lo = 0, hi = 256;
        while (lo < hi) {
            int m = (lo + hi) >> 1;
            if (s_cdf[m] <= u) lo = m + 1; else hi = m;
        }
        int below = lo - 1; if (below > 255) below = 255; if (below < 0) below = 0;
        int above = lo;     if (above > 255) above = 255;
        float cg0 = s_cdf[below], cg1 = s_cdf[above];
        float bg0 = d_init_val(below), bg1 = d_init_val(above);
        float den = cg1 - cg0;
        if (den < 1e-5f) den = 1.0f;
        float t = (u - cg0) / den;
        s_dfine[tid] = bg0 + t * (bg1 - bg0);
    }
    __syncthreads();                                  // B4

    // ---- merge coarse(64)+fine(64) ----
    if (tid < 64) {
        float v = d_coarse_val(tid);
        int lo = 0, hi = 64;
        while (lo < hi) {
            int m = (lo + hi) >> 1;
            if (s_dfine[m] < v) lo = m + 1; else hi = m;
        }
        s_dall[tid + lo] = v;
    } else if (tid < 128) {
        int j = tid - 64;
        float v = s_dfine[j];
        int lo = 0, hi = 64;
        while (lo < hi) {
            int m = (lo + hi) >> 1;
            if (d_coarse_val(m) <= v) lo = m + 1; else hi = m;
        }
        s_dall[j + lo] = v;
    }
    __syncthreads();                                  // B5

    // ================= Phase 2 =================
    float dall = 0.0f, delta2 = 1e10f;
    if (tid < 128) {
        dall = s_dall[tid];
        if (tid < 127) delta2 = s_dall[tid + 1] - dall;
        float px = ox + dx * dall, py = oy + dy * dall, pz = oz + dz * dall;
        s_xn[0][tid] = px * innorm - 1.0f;
        s_xn[1][tid] = py * innorm - 1.0f;
        s_xn[2][tid] = pz * innorm - 1.0f;
    }
    __syncthreads();                                  // B6

    const int samp = tid & 127;
    const int half = tid >> 7;
    float xnx = s_xn[0][samp], xny = s_xn[1][samp], xnz = s_xn[2][samp];

    // sdf gather first (waves 0-1 only; wave-uniform branch)
    float sdf2 = 0.0f;
    if (tid < 128)
        sdf2 = PACKED ? tri_sdf_rec((const float*)recs, xnx, xny, xnz)
                      : tri_sdf_vol(sdfv, xnx, xny, xnz);

    // attr gather (all 256 threads; tau applied later -> overlaps the scan)
    float acc[12];
#pragma unroll
    for (int c = 0; c < 12; c++) acc[c] = 0.0f;
    if (PACKED) tri_attr_rec(recs, xnx, xny, xnz, acc, half);
    else        tri_attr_planes(attr, xnx, xny, xnz, acc, half);

    // sigma chain + product scan over 128 (waves 0-1)
    float fv = 1.0f, a2 = 0.0f;
    if (tid < 128) {
        float e2 = expf(-fabsf(sdf2) / beta);
        float sig2 = alpha * ((sdf2 >= 0.0f) ? 0.5f * e2 : (1.0f - 0.5f * e2));
        float tr2 = expf(-sig2 * delta2);
        a2 = 1.0f - tr2;
        fv = tr2 + 1e-10f;
    }
    float incl3 = wave_scan_prod(fv, lane);
    if (tid == 63) s_pC = incl3;
    __syncthreads();                                  // B7
    if (tid < 128) {
        float offp2 = (wv == 0) ? 1.0f : s_pC;
        float ex = __shfl_up(incl3, 1, 64);
        if (lane == 0) ex = 1.0f;
        float tau = a2 * ex * offp2;
        s_tau[tid] = tau;
    }
    __syncthreads();                                  // B8
    float tau = s_tau[samp];

    // weighted per-wave butterfly reductions
    float red[15];
#pragma unroll
    for (int c = 0; c < 15; c++) red[c] = 0.0f;
    if (half == 0) {
#pragma unroll
        for (int c = 0; c < 12; c++) red[c] = tau * acc[c];
        red[12] = tau;
        red[13] = tau * dall;
        red[14] = sdf2;
    } else {
#pragma unroll
        for (int c = 0; c < 11; c++) red[c] = tau * acc[c];
    }
#pragma unroll
    for (int c = 0; c < 15; c++) {
        float v = wave_reduce_add(red[c]);
        if (lane == 0) s_wred[wv][c] = v;
    }
    __syncthreads();                                  // B9

    if (tid < 26) {
        float s;
        if (tid < 12)      s = s_wred[0][tid] + s_wred[1][tid];
        else if (tid < 23) s = s_wred[2][tid - 12] + s_wred[3][tid - 12];
        else               s = s_wred[0][tid - 11] + s_wred[1][tid - 11];
        s_sum[tid] = s;
    }
    __syncthreads();                                  // B10

    if (tid < 3) {
        out[r * 3 + tid] = s_sum[tid];
    } else if (tid < 23) {
        out[5 * R + r * 20 + (tid - 3)] = s_sum[tid];
    } else if (tid == 23) {
        float dist = s_sum[24] / (s_sum[23] + 1e-10f);
        out[3 * R + r] = dist / dr;
    } else if (tid == 24) {
        out[4 * R + r] = (s_sum[25] != 128.0f) ? 1.0f : 0.0f;
    }
}

extern "C" void kernel_launch(void* const* d_in, const int* in_sizes, int n_in,
                              void* d_out, int out_size, void* d_ws, size_t ws_size,
                              hipStream_t stream) {
    const float* rays = (const float*)d_in[0];
    const float* attr = (const float*)d_in[1];
    const float* sdfv = (const float*)d_in[2];
    const float* lnb  = (const float*)d_in[3];
    float* out = (float*)d_out;
    int R = in_sizes[0] / 6;

    bool packed = (ws_size >= WS_NEED) && (((uintptr_t)d_ws & 15) == 0);
    if (packed) {
        uintv4* recs = (uintv4*)d_ws;
        repack_kernel<<<dim3(VOXSTRIDE / 256), dim3(256), 0, stream>>>(attr, sdfv, recs);
        volrender_kernel<true><<<dim3(R), dim3(256), 0, stream>>>(
            rays, attr, sdfv, recs, lnb, out, R);
    } else {
        volrender_kernel<false><<<dim3(R), dim3(256), 0, stream>>>(
            rays, attr, sdfv, (const uintv4*)nullptr, lnb, out, R);
    }
}

// Round 5
// 398.284 us; speedup vs baseline: 1.2486x; 1.2486x over previous
//
#include <hip/hip_runtime.h>
#include <hip/hip_fp16.h>
#include <math.h>

#define DIM 128
#define VOXSTRIDE (DIM*DIM*DIM)
#define CATT 23
#define NEARF 0.2f
#define FARF 6.0f
#define WS_NEED ((size_t)VOXSTRIDE * 64ull)

typedef unsigned uintv4 __attribute__((ext_vector_type(4)));

// d_init: linspace(NEAR, FAR, 256)
__device__ __forceinline__ float d_init_val(int i) {
    float t = (float)i * (1.0f / 255.0f);
    return NEARF * (1.0f - t) + FARF * t;
}
// d_coarse: linspace(NEAR, FAR, 64)
__device__ __forceinline__ float d_coarse_val(int i) {
    float t = (float)i * (1.0f / 63.0f);
    return NEARF * (1.0f - t) + FARF * t;
}

// ---------- corner setup ----------
__device__ __forceinline__ void setup_ac_border(float x, float y, float z,
                                                float* i0, float* fr) {
    float c[3] = {x, y, z};
#pragma unroll
    for (int a = 0; a < 3; a++) {
        float v = (c[a] + 1.0f) * 0.5f * 127.0f;
        v = fminf(fmaxf(v, 0.0f), 127.0f);
        float f = floorf(v);
        i0[a] = f; fr[a] = v - f;
    }
}
__device__ __forceinline__ void setup_nac_zeros(float x, float y, float z,
                                                float* i0, float* fr) {
    float c[3] = {x, y, z};
#pragma unroll
    for (int a = 0; a < 3; a++) {
        float v = ((c[a] + 1.0f) * 128.0f - 1.0f) * 0.5f;
        float f = floorf(v);
        i0[a] = f; fr[a] = v - f;
    }
}

// trilinear SDF from fp32 volume (align_corners=True, border)
__device__ __forceinline__ float tri_sdf_vol(const float* __restrict__ vol,
                                             float x, float y, float z) {
    float i0[3], fr[3];
    setup_ac_border(x, y, z, i0, fr);
    float res = 0.0f;
#pragma unroll
    for (int corner = 0; corner < 8; corner++) {
        float w = 1.0f;
        int gi[3];
#pragma unroll
        for (int a = 0; a < 3; a++) {
            int off = (corner >> a) & 1;
            float iv = i0[a] + (float)off;
            w *= off ? fr[a] : (1.0f - fr[a]);
            iv = fminf(fmaxf(iv, 0.0f), 127.0f);
            gi[a] = (int)iv;
        }
        int idx = (gi[0] * DIM + gi[1]) * DIM + gi[2];
        res += vol[idx] * w;
    }
    return res;
}

// trilinear SDF from packed records (fp32 at dword 12 of 16-dword record)
__device__ __forceinline__ float tri_sdf_rec(const float* __restrict__ recf,
                                             float x, float y, float z) {
    float i0[3], fr[3];
    setup_ac_border(x, y, z, i0, fr);
    float res = 0.0f;
#pragma unroll
    for (int corner = 0; corner < 8; corner++) {
        float w = 1.0f;
        int gi[3];
#pragma unroll
        for (int a = 0; a < 3; a++) {
            int off = (corner >> a) & 1;
            float iv = i0[a] + (float)off;
            w *= off ? fr[a] : (1.0f - fr[a]);
            iv = fminf(fmaxf(iv, 0.0f), 127.0f);
            gi[a] = (int)iv;
        }
        int idx = (gi[0] * DIM + gi[1]) * DIM + gi[2];
        res += recf[idx * 16 + 12] * w;
    }
    return res;
}

__device__ __forceinline__ void unpack16(uintv4 a, uintv4 b, float* v) {
    unsigned us[8] = {a.x, a.y, a.z, a.w, b.x, b.y, b.z, b.w};
#pragma unroll
    for (int i = 0; i < 8; i++) {
        v[2 * i]     = __half2float(__ushort_as_half((unsigned short)(us[i] & 0xffffu)));
        v[2 * i + 1] = __half2float(__ushort_as_half((unsigned short)(us[i] >> 16)));
    }
}

// attr trilinear (w-weighted, NOT tau-weighted) from packed fp16 records
__device__ __forceinline__ void tri_attr_rec(const uintv4* __restrict__ recs,
                                             float x, float y, float z,
                                             float* acc, int half) {
    float i0[3], fr[3];
    setup_nac_zeros(x, y, z, i0, fr);
#pragma unroll
    for (int corner = 0; corner < 8; corner++) {
        float w = 1.0f;
        bool valid = true;
        int gi[3];
#pragma unroll
        for (int a = 0; a < 3; a++) {
            int off = (corner >> a) & 1;
            float iv = i0[a] + (float)off;
            w *= off ? fr[a] : (1.0f - fr[a]);
            valid = valid && (iv >= 0.0f) && (iv <= 127.0f);
            iv = fminf(fmaxf(iv, 0.0f), 127.0f);
            gi[a] = (int)iv;
        }
        if (!valid) continue;
        int idx = (gi[0] * DIM + gi[1]) * DIM + gi[2];
        const uintv4* q = recs + (size_t)idx * 4 + half;  // h0: q0,q1; h1: q1,q2
        uintv4 qa = q[0], qb = q[1];
        float vals[16];
        unpack16(qa, qb, vals);
        if (half == 0) {
#pragma unroll
            for (int c = 0; c < 12; c++) acc[c] += w * vals[c];
        } else {
#pragma unroll
            for (int c = 0; c < 11; c++) acc[c] += w * vals[c + 4];
        }
    }
}

// fallback: fp32 planes
__device__ __forceinline__ void tri_attr_planes(const float* __restrict__ vol,
                                                float x, float y, float z,
                                                float* acc, int half) {
    float i0[3], fr[3];
    setup_nac_zeros(x, y, z, i0, fr);
    int c0 = half ? 12 : 0;
    int nc = half ? 11 : 12;
#pragma unroll
    for (int corner = 0; corner < 8; corner++) {
        float w = 1.0f;
        bool valid = true;
        int gi[3];
#pragma unroll
        for (int a = 0; a < 3; a++) {
            int off = (corner >> a) & 1;
            float iv = i0[a] + (float)off;
            w *= off ? fr[a] : (1.0f - fr[a]);
            valid = valid && (iv >= 0.0f) && (iv <= 127.0f);
            iv = fminf(fmaxf(iv, 0.0f), 127.0f);
            gi[a] = (int)iv;
        }
        if (!valid) continue;
        int idx = (gi[0] * DIM + gi[1]) * DIM + gi[2];
        for (int c = 0; c < nc; c++)
            acc[c] += w * vol[(c0 + c) * VOXSTRIDE + idx];
    }
}

// ---------- repack: NT plane reads, LDS-staged full-line coalesced writes ---
// LDS record stride 5 uintv4 (80 B) -> bank-conflict-clean b128 access.
__global__ __launch_bounds__(256) void repack_kernel(
    const float* __restrict__ attr, const float* __restrict__ sdfv,
    uintv4* __restrict__ recs) {
    __shared__ uintv4 s_rec[256 * 5];   // 20 KB
    const int tid = threadIdx.x;
    const int v = blockIdx.x * 256 + tid;
    float a[24];
#pragma unroll
    for (int c = 0; c < CATT; c++)
        a[c] = __builtin_nontemporal_load(attr + (size_t)c * VOXSTRIDE + v);
    a[23] = 0.0f;
    float s = sdfv[v];   // cached: phase-1 reuses the sdf volume
    unsigned u[12];
#pragma unroll
    for (int p = 0; p < 12; p++) {
        __half2 h = __float22half2_rn(make_float2(a[2 * p], a[2 * p + 1]));
        u[p] = __builtin_bit_cast(unsigned, h);
    }
    uintv4 q0 = {u[0], u[1], u[2], u[3]};
    uintv4 q1 = {u[4], u[5], u[6], u[7]};
    uintv4 q2 = {u[8], u[9], u[10], u[11]};
    uintv4 q3 = {__float_as_uint(s), 0u, 0u, 0u};
    s_rec[tid * 5 + 0] = q0;
    s_rec[tid * 5 + 1] = q1;
    s_rec[tid * 5 + 2] = q2;
    s_rec[tid * 5 + 3] = q3;
    __syncthreads();
    // block writes 256 records = 1024 uintv4, lane-consecutive (full lines)
    uintv4* dst = recs + (size_t)blockIdx.x * 1024;
#pragma unroll
    for (int k = 0; k < 4; k++) {
        int g = k * 256 + tid;             // linear uintv4 index in block tile
        int rec = g >> 2, qq = g & 3;
        dst[g] = s_rec[rec * 5 + qq];
    }
}

// ---------- wave-level scans/reductions (width 64, no barriers) ----------
__device__ __forceinline__ float wave_scan_prod(float v, int lane) {
#pragma unroll
    for (int off = 1; off < 64; off <<= 1) {
        float o = __shfl_up(v, off, 64);
        if (lane >= off) v *= o;
    }
    return v;
}
__device__ __forceinline__ float wave_scan_add(float v, int lane) {
#pragma unroll
    for (int off = 1; off < 64; off <<= 1) {
        float o = __shfl_up(v, off, 64);
        if (lane >= off) v += o;
    }
    return v;
}
__device__ __forceinline__ float wave_reduce_add(float v) {
#pragma unroll
    for (int m = 32; m >= 1; m >>= 1) v += __shfl_xor(v, m, 64);
    return v;
}

template <bool PACKED>
__global__ __launch_bounds__(256, 4) void volrender_kernel(
    const float* __restrict__ rays,
    const float* __restrict__ attr,
    const float* __restrict__ sdfv,
    const uintv4* __restrict__ recs,
    const float* __restrict__ lnb,
    float* __restrict__ out, int R) {
    __shared__ float s_cdf[256];
    __shared__ float s_dfine[64];
    __shared__ float s_dall[128];
    __shared__ float s_xn[3][128];
    __shared__ float s_tau[128];
    __shared__ float s_pA[4], s_pB[4];
    __shared__ float s_pC;
    __shared__ float s_wred[4][16];
    __shared__ float s_sum[26];

    const int r = blockIdx.x;
    const int tid = threadIdx.x;
    const int lane = tid & 63;
    const int wv = tid >> 6;

    float ox = rays[r * 6 + 0], oy = rays[r * 6 + 1], oz = rays[r * 6 + 2];
    float dx = rays[r * 6 + 3], dy = rays[r * 6 + 4], dz = rays[r * 6 + 5];
    dx = (fabsf(dx) < 1e-6f) ? 1e-6f : dx;
    dy = (fabsf(dy) < 1e-6f) ? 1e-6f : dy;
    dz = (fabsf(dz) < 1e-6f) ? 1e-6f : dz;
    float dr = sqrtf(dx * dx + dy * dy + dz * dz);
    float invdr = 1.0f / dr;
    dx *= invdr; dy *= invdr; dz *= invdr;

    const float beta = expf(lnb[0] * 10.0f);
    const float alpha = 1.0f / beta;
    const float innorm = 2.0f / 5.12f;

    // ================= Phase 1: 256 init samples =================
    float d0 = d_init_val(tid);
    float sdf0;
    {
        float px = ox + dx * d0, py = oy + dy * d0, pz = oz + dz * d0;
        sdf0 = tri_sdf_vol(sdfv, px * innorm - 1.0f, py * innorm - 1.0f,
                           pz * innorm - 1.0f);
    }
    float delta0 = (tid < 255) ? (d_init_val(tid + 1) - d0) : 1e10f;
    float e0 = expf(-fabsf(sdf0) / beta);
    float sig0 = alpha * ((sdf0 >= 0.0f) ? 0.5f * e0 : (1.0f - 0.5f * e0));
    float tr0 = expf(-sig0 * delta0);
    float a0 = 1.0f - tr0;

    // exclusive product scan (transmittance)
    float inclp = wave_scan_prod(tr0 + 1e-10f, lane);
    if (lane == 63) s_pA[wv] = inclp;
    __syncthreads();                                  // B1
    float offp = 1.0f;
#pragma unroll
    for (int j = 0; j < 3; j++) if (j < wv) offp *= s_pA[j];
    float exclp = __shfl_up(inclp, 1, 64);
    if (lane == 0) exclp = 1.0f;
    float T0 = exclp * offp;
    float w0 = a0 * T0;

    // exclusive add scan (cdf)
    float wp = (tid < 255) ? (w0 + 1e-5f) : 0.0f;
    float incla = wave_scan_add(wp, lane);
    if (lane == 63) s_pB[wv] = incla;
    __syncthreads();                                  // B2
    float offa = 0.0f, tot = 0.0f;
#pragma unroll
    for (int j = 0; j < 4; j++) {
        float pj = s_pB[j];
        tot += pj;
        if (j < wv) offa += pj;
    }
    float excla = __shfl_up(incla, 1, 64);
    if (lane == 0) excla = 0.0f;
    float invw = 1.0f / tot;
    s_cdf[tid] = (excla + offa) * invw;               // cdf[0]=0, cdf[255]=1
    __syncthreads();                                  // B3

    // ---- sample_pdf ----
    if (tid < 64) {
        float u = ((float)tid + 0.5f) * (1.0f / 64.0f);
        int lo = 0, hi = 256;
        while (lo < hi) {
            int m = (lo + hi) >> 1;
            if (s_cdf[m] <= u) lo = m + 1; else hi = m;
        }
        int below = lo - 1; if (below > 255) below = 255; if (below < 0) below = 0;
        int above = lo;     if (above > 255) above = 255;
        float cg0 = s_cdf[below], cg1 = s_cdf[above];
        float bg0 = d_init_val(below), bg1 = d_init_val(above);
        float den = cg1 - cg0;
        if (den < 1e-5f) den = 1.0f;
        float t = (u - cg0) / den;
        s_dfine[tid] = bg0 + t * (bg1 - bg0);
    }
    __syncthreads();                                  // B4

    // ---- merge coarse(64)+fine(64) ----
    if (tid < 64) {
        float v = d_coarse_val(tid);
        int lo = 0, hi = 64;
        while (lo < hi) {
            int m = (lo + hi) >> 1;
            if (s_dfine[m] < v) lo = m + 1; else hi = m;
        }
        s_dall[tid + lo] = v;
    } else if (tid < 128) {
        int j = tid - 64;
        float v = s_dfine[j];
        int lo = 0, hi = 64;
        while (lo < hi) {
            int m = (lo + hi) >> 1;
            if (d_coarse_val(m) <= v) lo = m + 1; else hi = m;
        }
        s_dall[j + lo] = v;
    }
    __syncthreads();                                  // B5

    // ================= Phase 2 =================
    float dall = 0.0f, delta2 = 1e10f;
    if (tid < 128) {
        dall = s_dall[tid];
        if (tid < 127) delta2 = s_dall[tid + 1] - dall;
        float px = ox + dx * dall, py = oy + dy * dall, pz = oz + dz * dall;
        s_xn[0][tid] = px * innorm - 1.0f;
        s_xn[1][tid] = py * innorm - 1.0f;
        s_xn[2][tid] = pz * innorm - 1.0f;
    }
    __syncthreads();                                  // B6

    const int samp = tid & 127;
    const int half = tid >> 7;
    float xnx = s_xn[0][samp], xny = s_xn[1][samp], xnz = s_xn[2][samp];

    // sdf gather first (waves 0-1 only; wave-uniform branch)
    float sdf2 = 0.0f;
    if (tid < 128)
        sdf2 = PACKED ? tri_sdf_rec((const float*)recs, xnx, xny, xnz)
                      : tri_sdf_vol(sdfv, xnx, xny, xnz);

    // attr gather (all 256 threads; tau applied later -> overlaps the scan)
    float acc[12];
#pragma unroll
    for (int c = 0; c < 12; c++) acc[c] = 0.0f;
    if (PACKED) tri_attr_rec(recs, xnx, xny, xnz, acc, half);
    else        tri_attr_planes(attr, xnx, xny, xnz, acc, half);

    // sigma chain + product scan over 128 (waves 0-1)
    float fv = 1.0f, a2 = 0.0f;
    if (tid < 128) {
        float e2 = expf(-fabsf(sdf2) / beta);
        float sig2 = alpha * ((sdf2 >= 0.0f) ? 0.5f * e2 : (1.0f - 0.5f * e2));
        float tr2 = expf(-sig2 * delta2);
        a2 = 1.0f - tr2;
        fv = tr2 + 1e-10f;
    }
    float incl3 = wave_scan_prod(fv, lane);
    if (tid == 63) s_pC = incl3;
    __syncthreads();                                  // B7
    if (tid < 128) {
        float offp2 = (wv == 0) ? 1.0f : s_pC;
        float ex = __shfl_up(incl3, 1, 64);
        if (lane == 0) ex = 1.0f;
        float tau = a2 * ex * offp2;
        s_tau[tid] = tau;
    }
    __syncthreads();                                  // B8
    float tau = s_tau[samp];

    // weighted per-wave butterfly reductions
    float red[15];
#pragma unroll
    for (int c = 0; c < 15; c++) red[c] = 0.0f;
    if (half == 0) {
#pragma unroll
        for (int c = 0; c < 12; c++) red[c] = tau * acc[c];
        red[12] = tau;
        red[13] = tau * dall;
        red[14] = sdf2;
    } else {
#pragma unroll
        for (int c = 0; c < 11; c++) red[c] = tau * acc[c];
    }
#pragma unroll
    for (int c = 0; c < 15; c++) {
        float v = wave_reduce_add(red[c]);
        if (lane == 0) s_wred[wv][c] = v;
    }
    __syncthreads();                                  // B9

    if (tid < 26) {
        float s;
        if (tid < 12)      s = s_wred[0][tid] + s_wred[1][tid];
        else if (tid < 23) s = s_wred[2][tid - 12] + s_wred[3][tid - 12];
        else               s = s_wred[0][tid - 11] + s_wred[1][tid - 11];
        s_sum[tid] = s;
    }
    __syncthreads();                                  // B10

    if (tid < 3) {
        out[r * 3 + tid] = s_sum[tid];
    } else if (tid < 23) {
        out[5 * R + r * 20 + (tid - 3)] = s_sum[tid];
    } else if (tid == 23) {
        float dist = s_sum[24] / (s_sum[23] + 1e-10f);
        out[3 * R + r] = dist / dr;
    } else if (tid == 24) {
        out[4 * R + r] = (s_sum[25] != 128.0f) ? 1.0f : 0.0f;
    }
}

extern "C" void kernel_launch(void* const* d_in, const int* in_sizes, int n_in,
                              void* d_out, int out_size, void* d_ws, size_t ws_size,
                              hipStream_t stream) {
    const float* rays = (const float*)d_in[0];
    const float* attr = (const float*)d_in[1];
    const float* sdfv = (const float*)d_in[2];
    const float* lnb  = (const float*)d_in[3];
    float* out = (float*)d_out;
    int R = in_sizes[0] / 6;

    bool packed = (ws_size >= WS_NEED) && (((uintptr_t)d_ws & 15) == 0);
    if (packed) {
        uintv4* recs = (uintv4*)d_ws;
        repack_kernel<<<dim3(VOXSTRIDE / 256), dim3(256), 0, stream>>>(attr, sdfv, recs);
        volrender_kernel<true><<<dim3(R), dim3(256), 0, stream>>>(
            rays, attr, sdfv, recs, lnb, out, R);
    } else {
        volrender_kernel<false><<<dim3(R), dim3(256), 0, stream>>>(
            rays, attr, sdfv, (const uintv4*)nullptr, lnb, out, R);
    }
}